// Round 8
// baseline (53.016 us; speedup 1.0000x reference)
//
#include <hip/hip_runtime.h>

typedef __attribute__((ext_vector_type(8))) short bf16x8;
typedef __attribute__((ext_vector_type(4))) float f32x4;
typedef __attribute__((ext_vector_type(4))) short s16x4;

#define MAGIC 0x5A5A5A5Au

__device__ __forceinline__ unsigned short f2bf(float f) {
    unsigned int u = __builtin_bit_cast(unsigned int, f);
    u += 0x7fffu + ((u >> 16) & 1u);   // round-to-nearest-even
    return (unsigned short)(u >> 16);
}
__device__ __forceinline__ float bf2f(unsigned short h) {
    return __builtin_bit_cast(float, ((unsigned int)h) << 16);
}

// Fused kernel. d_ws: [0,32768) apk (A packed bf16, u32-word-atomic writes);
// [32768,32768+2048) slots[512] publish flags.
//
// A[i][j] = (i==j) ? 0 : sum_d w[i,field[j],d]*w[j,field[i],d]; symmetric and
// bit-identical across the diagonal (elementwise products commute, same d-order)
// so one packing serves as both MFMA operands. Packing (u16 view):
//   apk[((kt*8+nt)*64+lane)*8+r] <-> A[kt*32+(lane>>4)*8+r][nt*16+(lane&15)]
// u32 word W = ((kt*8+nt)*64+lane)*4+rp holds r=2rp (lo) and r=2rp+1 (hi):
// same j, adjacent i -> one thread computes both, writes ONE u32 atomically
// (agent scope -> coherent point; no cross-XCD dirty-line false sharing).
__global__ __launch_bounds__(256, 2)
void ffm_fused(const float* __restrict__ x, const float* __restrict__ w,
               const int* __restrict__ field, float* __restrict__ out,
               unsigned int* __restrict__ apk32, unsigned int* __restrict__ slots,
               int nTiles, int tilesPerWG) {
    __shared__ __align__(16) unsigned short Xl[2][64 * 128];  // 2 x 16 KiB bf16, swizzled
    const int tid  = threadIdx.x;
    const int lane = tid & 63;
    const int wv   = tid >> 6;     // wave 0..3 owns rows [wv*16, wv*16+16)
    const int g    = lane >> 4;
    const int c    = lane & 15;
    const int b    = blockIdx.x;

    const int tile0 = b * tilesPerWG;
    const bool haveWork = tile0 < nTiles;

    // ---- 1) Issue first-tile x loads immediately (HBM busy during build/poll)
    f32x4 xr[8];
    if (haveWork) {
        const f32x4* src = reinterpret_cast<const f32x4*>(x) + (size_t)tile0 * 2048;
#pragma unroll
        for (int i = 0; i < 8; ++i) xr[i] = src[i * 256 + tid];
    }

    // ---- 2) Build this block's 16 u32 words of A (8192 words / 512 blocks)
    if (tid < 16) {
        int W    = b * 16 + tid;
        int rp   = W & 3;
        int lw   = (W >> 2) & 63;
        int nt   = (W >> 8) & 7;
        int kt   = W >> 11;
        int i0   = kt * 32 + (lw >> 4) * 8 + rp * 2;   // and i1 = i0+1
        int j    = nt * 16 + (lw & 15);
        int fj   = field[j];
        const float* wi0 = w + (i0 * 16 + fj) * 16;
        const float* wi1 = w + ((i0 + 1) * 16 + fj) * 16;
        const float* wj0 = w + (j * 16 + field[i0]) * 16;
        const float* wj1 = w + (j * 16 + field[i0 + 1]) * 16;
        float s0 = 0.f, s1 = 0.f;
#pragma unroll
        for (int d = 0; d < 16; ++d) { s0 += wi0[d] * wj0[d]; s1 += wi1[d] * wj1[d]; }
        if (i0 == j)     s0 = 0.f;
        if (i0 + 1 == j) s1 = 0.f;
        unsigned int val = (unsigned int)f2bf(s0) | ((unsigned int)f2bf(s1) << 16);
        __hip_atomic_store(&apk32[W], val, __ATOMIC_RELAXED, __HIP_MEMORY_SCOPE_AGENT);
    }
    __syncthreads();
    if (tid == 0)
        __hip_atomic_store(&slots[b], MAGIC, __ATOMIC_RELEASE, __HIP_MEMORY_SCOPE_AGENT);

    // ---- 3) Poll all 512 flags (acquire orders the subsequent apk reads)
    while (__hip_atomic_load(&slots[tid],       __ATOMIC_ACQUIRE, __HIP_MEMORY_SCOPE_AGENT) != MAGIC ||
           __hip_atomic_load(&slots[tid + 256], __ATOMIC_ACQUIRE, __HIP_MEMORY_SCOPE_AGENT) != MAGIC)
        __builtin_amdgcn_s_sleep(8);
    __syncthreads();

    if (!haveWork) return;

    // ---- 4) A fragments into registers (128 VGPR)
    const unsigned short* apk = reinterpret_cast<const unsigned short*>(apk32);
    bf16x8 bfrag[4][8];
#pragma unroll
    for (int kt = 0; kt < 4; ++kt)
#pragma unroll
        for (int nt = 0; nt < 8; ++nt)
            bfrag[kt][nt] = *reinterpret_cast<const bf16x8*>(apk + ((kt * 8 + nt) * 64 + lane) * 8);

    const int myrow = wv * 16 + c;
    const int rowbase = myrow * 128;
    const int xv = (myrow & 7) << 3;

    // ---- 5) R3-proven main loop (reg-stage, prefetch before barrier)
    int buf = 0;
    for (int t = 0; t < tilesPerWG; ++t) {
        int tile = tile0 + t;
        if (tile >= nTiles) break;

        // Stage regs -> LDS bf16, XOR swizzle (short idx ^= (row&7)<<3).
#pragma unroll
        for (int i = 0; i < 8; ++i) {
            int row = i * 8 + (tid >> 5);
            int k   = (tid & 31) * 4;
            int sw  = row * 128 + (k ^ ((row & 7) << 3));
            s16x4 s4;
            s4.x = (short)f2bf(xr[i][0]);
            s4.y = (short)f2bf(xr[i][1]);
            s4.z = (short)f2bf(xr[i][2]);
            s4.w = (short)f2bf(xr[i][3]);
            *reinterpret_cast<s16x4*>(&Xl[buf][sw]) = s4;
        }
        // Prefetch next tile before the barrier (in flight across compute).
        if (t + 1 < tilesPerWG && tile + 1 < nTiles) {
            const f32x4* src = reinterpret_cast<const f32x4*>(x) + (size_t)(tile + 1) * 2048;
#pragma unroll
            for (int i = 0; i < 8; ++i) xr[i] = src[i * 256 + tid];
        }
        __syncthreads();

        // Yt = A(128x128) * X^T(128x16): acc[q] = Y[myrow][q*16 + g*4 + r].
        f32x4 acc[8];
#pragma unroll
        for (int q = 0; q < 8; ++q) acc[q] = (f32x4){0.f, 0.f, 0.f, 0.f};
#pragma unroll
        for (int kt = 0; kt < 4; ++kt) {
            int k0 = kt * 32 + g * 8;   // B-operand: col=c (-> row myrow), k-slots g*8+r
            bf16x8 xa = *reinterpret_cast<const bf16x8*>(
                &Xl[buf][rowbase + (k0 ^ xv)]);
#pragma unroll
            for (int q = 0; q < 8; ++q)
                acc[q] = __builtin_amdgcn_mfma_f32_16x16x32_bf16(bfrag[kt][q], xa, acc[q], 0, 0, 0);
        }

        // Epilogue: sacc = sum over this lane's 32 i's of X[m][i]*Y[m][i].
        float sacc = 0.f;
#pragma unroll
        for (int q = 0; q < 8; ++q) {
            int ix = q * 16 + g * 4;
            s16x4 xs = *reinterpret_cast<const s16x4*>(&Xl[buf][rowbase + (ix ^ xv)]);
            sacc += bf2f((unsigned short)xs.x) * acc[q][0];
            sacc += bf2f((unsigned short)xs.y) * acc[q][1];
            sacc += bf2f((unsigned short)xs.z) * acc[q][2];
            sacc += bf2f((unsigned short)xs.w) * acc[q][3];
        }
        sacc += __shfl_xor(sacc, 16, 64);
        sacc += __shfl_xor(sacc, 32, 64);
        if (g == 0) out[(size_t)tile * 64 + myrow] = 0.5f * sacc;

        buf ^= 1;
    }
}

extern "C" void kernel_launch(void* const* d_in, const int* in_sizes, int n_in,
                              void* d_out, int out_size, void* d_ws, size_t ws_size,
                              hipStream_t stream) {
    const float* x     = (const float*)d_in[0];
    const float* w     = (const float*)d_in[1];
    const int*   field = (const int*)d_in[2];
    float* outp        = (float*)d_out;
    unsigned int* apk32 = (unsigned int*)d_ws;                       // 32 KiB
    unsigned int* slots = (unsigned int*)((char*)d_ws + 32768);     // 2 KiB

    int B = in_sizes[0] / 128;
    int nTiles = B / 64;                       // 2048 for B=131072
    const int GRID = 512;                      // exactly 2 blocks/CU -> all resident
    int tpw = (nTiles + GRID - 1) / GRID;      // 4
    ffm_fused<<<GRID, 256, 0, stream>>>(x, w, field, outp, apk32, slots, nTiles, tpw);
}

// Round 9
// 28.120 us; speedup vs baseline: 1.8854x; 1.8854x over previous
//
#include <hip/hip_runtime.h>

typedef __attribute__((ext_vector_type(8))) short bf16x8;
typedef __attribute__((ext_vector_type(4))) float f32x4;
typedef __attribute__((ext_vector_type(4))) short s16x4;
typedef __attribute__((ext_vector_type(2))) unsigned long long u64x2;

#define MAGIC 0x5A5A5A5Au

__device__ __forceinline__ unsigned short f2bf(float f) {
    unsigned int u = __builtin_bit_cast(unsigned int, f);
    u += 0x7fffu + ((u >> 16) & 1u);   // round-to-nearest-even
    return (unsigned short)(u >> 16);
}
__device__ __forceinline__ float bf2f(unsigned short h) {
    return __builtin_bit_cast(float, ((unsigned int)h) << 16);
}

// Fused kernel. d_ws: [0,32768) apk (A packed bf16; all access via agent-scope
// relaxed atomics = coherence point, no cross-XCD dirty-line aliasing);
// [32768,32768+2048) slots[512] publish flags.
//
// A[i][j] = (i==j) ? 0 : sum_d w[i,field[j],d]*w[j,field[i],d]; symmetric and
// bit-identical across the diagonal -> one packing serves as both MFMA operands.
// Packing (u16 view): apk[((kt*8+nt)*64+lane)*8+r] <-> A[kt*32+(lane>>4)*8+r][nt*16+(lane&15)]
// u32 word W = ((kt*8+nt)*64+lane)*4+rp holds r=2rp (lo), r=2rp+1 (hi).
//
// Sync design (R8 lesson): NO acquire anywhere. Writers: relaxed atomic data
// stores + RELEASE flag (data at coherence point before flag visible).
// Readers: RELAXED flag polls (no cache-maintenance side effects), then
// relaxed atomic data loads (served from coherence point). Replays: flags
// remain MAGIC -> one-sweep exit; apk rewritten bit-identically (benign).
__global__ __launch_bounds__(256, 2)
void ffm_fused(const float* __restrict__ x, const float* __restrict__ w,
               const int* __restrict__ field, float* __restrict__ out,
               unsigned int* __restrict__ apk32, unsigned int* __restrict__ slots,
               int nTiles, int tilesPerWG) {
    __shared__ __align__(16) unsigned short Xl[2][64 * 128];  // 2 x 16 KiB bf16, swizzled
    const int tid  = threadIdx.x;
    const int lane = tid & 63;
    const int wv   = tid >> 6;     // wave 0..3 owns rows [wv*16, wv*16+16)
    const int g    = lane >> 4;
    const int c    = lane & 15;
    const int b    = blockIdx.x;

    const int tile0 = b * tilesPerWG;

    // ---- 1) Issue first-tile x loads immediately (memory busy during build/poll)
    f32x4 xr[8];
    {
        const f32x4* src = reinterpret_cast<const f32x4*>(x) + (size_t)tile0 * 2048;
#pragma unroll
        for (int i = 0; i < 8; ++i) xr[i] = src[i * 256 + tid];
    }

    // ---- 2) Build this block's 16 u32 words of A (8192 words / 512 blocks)
    if (tid < 16) {
        int W    = b * 16 + tid;
        int rp   = W & 3;
        int lw   = (W >> 2) & 63;
        int nt   = (W >> 8) & 7;
        int kt   = W >> 11;
        int i0   = kt * 32 + (lw >> 4) * 8 + rp * 2;   // and i1 = i0+1
        int j    = nt * 16 + (lw & 15);
        int fj   = field[j];
        const float* wi0 = w + (i0 * 16 + fj) * 16;
        const float* wi1 = w + ((i0 + 1) * 16 + fj) * 16;
        const float* wj0 = w + (j * 16 + field[i0]) * 16;
        const float* wj1 = w + (j * 16 + field[i0 + 1]) * 16;
        float s0 = 0.f, s1 = 0.f;
#pragma unroll
        for (int d = 0; d < 16; ++d) { s0 += wi0[d] * wj0[d]; s1 += wi1[d] * wj1[d]; }
        if (i0 == j)     s0 = 0.f;
        if (i0 + 1 == j) s1 = 0.f;
        unsigned int val = (unsigned int)f2bf(s0) | ((unsigned int)f2bf(s1) << 16);
        __hip_atomic_store(&apk32[W], val, __ATOMIC_RELAXED, __HIP_MEMORY_SCOPE_AGENT);
    }
    __syncthreads();
    if (tid == 0)
        __hip_atomic_store(&slots[b], MAGIC, __ATOMIC_RELEASE, __HIP_MEMORY_SCOPE_AGENT);

    // ---- 3) Poll all 512 flags with RELAXED loads (no invalidate storms)
    for (;;) {
        unsigned a0 = __hip_atomic_load(&slots[tid],       __ATOMIC_RELAXED, __HIP_MEMORY_SCOPE_AGENT);
        unsigned a1 = __hip_atomic_load(&slots[tid + 256], __ATOMIC_RELAXED, __HIP_MEMORY_SCOPE_AGENT);
        if (__syncthreads_and(a0 == MAGIC && a1 == MAGIC)) break;
        __builtin_amdgcn_s_sleep(16);
    }

    // ---- 4) A fragments into registers via relaxed atomic u64 pairs (128 VGPR)
    const unsigned long long* apk64 = reinterpret_cast<const unsigned long long*>(apk32);
    bf16x8 bfrag[4][8];
#pragma unroll
    for (int kt = 0; kt < 4; ++kt)
#pragma unroll
        for (int nt = 0; nt < 8; ++nt) {
            int idx = ((kt * 8 + nt) * 64 + lane) * 2;
            u64x2 v;
            v[0] = __hip_atomic_load(&apk64[idx],     __ATOMIC_RELAXED, __HIP_MEMORY_SCOPE_AGENT);
            v[1] = __hip_atomic_load(&apk64[idx + 1], __ATOMIC_RELAXED, __HIP_MEMORY_SCOPE_AGENT);
            bfrag[kt][nt] = __builtin_bit_cast(bf16x8, v);
        }

    const int myrow = wv * 16 + c;
    const int rowbase = myrow * 128;
    const int xv = (myrow & 7) << 3;

    // ---- 5) R3-proven main loop (reg-stage, prefetch before barrier)
    int buf = 0;
    for (int t = 0; t < tilesPerWG; ++t) {
        int tile = tile0 + t;
        if (tile >= nTiles) break;

        // Stage regs -> LDS bf16, XOR swizzle (short idx ^= (row&7)<<3).
#pragma unroll
        for (int i = 0; i < 8; ++i) {
            int row = i * 8 + (tid >> 5);
            int k   = (tid & 31) * 4;
            int sw  = row * 128 + (k ^ ((row & 7) << 3));
            s16x4 s4;
            s4.x = (short)f2bf(xr[i][0]);
            s4.y = (short)f2bf(xr[i][1]);
            s4.z = (short)f2bf(xr[i][2]);
            s4.w = (short)f2bf(xr[i][3]);
            *reinterpret_cast<s16x4*>(&Xl[buf][sw]) = s4;
        }
        // Prefetch next tile before the barrier (in flight across compute).
        if (t + 1 < tilesPerWG && tile + 1 < nTiles) {
            const f32x4* src = reinterpret_cast<const f32x4*>(x) + (size_t)(tile + 1) * 2048;
#pragma unroll
            for (int i = 0; i < 8; ++i) xr[i] = src[i * 256 + tid];
        }
        __syncthreads();

        // Yt = A(128x128) * X^T(128x16): acc[q] = Y[myrow][q*16 + g*4 + r].
        f32x4 acc[8];
#pragma unroll
        for (int q = 0; q < 8; ++q) acc[q] = (f32x4){0.f, 0.f, 0.f, 0.f};
#pragma unroll
        for (int kt = 0; kt < 4; ++kt) {
            int k0 = kt * 32 + g * 8;   // B-operand: col=c (-> row myrow), k-slots g*8+r
            bf16x8 xa = *reinterpret_cast<const bf16x8*>(
                &Xl[buf][rowbase + (k0 ^ xv)]);
#pragma unroll
            for (int q = 0; q < 8; ++q)
                acc[q] = __builtin_amdgcn_mfma_f32_16x16x32_bf16(bfrag[kt][q], xa, acc[q], 0, 0, 0);
        }

        // Epilogue: sacc = sum over this lane's 32 i's of X[m][i]*Y[m][i].
        float sacc = 0.f;
#pragma unroll
        for (int q = 0; q < 8; ++q) {
            int ix = q * 16 + g * 4;
            s16x4 xs = *reinterpret_cast<const s16x4*>(&Xl[buf][rowbase + (ix ^ xv)]);
            sacc += bf2f((unsigned short)xs.x) * acc[q][0];
            sacc += bf2f((unsigned short)xs.y) * acc[q][1];
            sacc += bf2f((unsigned short)xs.z) * acc[q][2];
            sacc += bf2f((unsigned short)xs.w) * acc[q][3];
        }
        sacc += __shfl_xor(sacc, 16, 64);
        sacc += __shfl_xor(sacc, 32, 64);
        if (g == 0) out[(size_t)tile * 64 + myrow] = 0.5f * sacc;

        buf ^= 1;
    }
}

extern "C" void kernel_launch(void* const* d_in, const int* in_sizes, int n_in,
                              void* d_out, int out_size, void* d_ws, size_t ws_size,
                              hipStream_t stream) {
    const float* x     = (const float*)d_in[0];
    const float* w     = (const float*)d_in[1];
    const int*   field = (const int*)d_in[2];
    float* outp        = (float*)d_out;
    unsigned int* apk32 = (unsigned int*)d_ws;                       // 32 KiB
    unsigned int* slots = (unsigned int*)((char*)d_ws + 32768);     // 2 KiB

    int B = in_sizes[0] / 128;
    int nTiles = B / 64;                       // 2048 for B=131072
    const int GRID = 512;                      // exactly 2 blocks/CU -> all resident
    int tpw = (nTiles + GRID - 1) / GRID;      // 4
    ffm_fused<<<GRID, 256, 0, stream>>>(x, w, field, outp, apk32, slots, nTiles, tpw);
}

// Round 10
// 26.676 us; speedup vs baseline: 1.9875x; 1.0541x over previous
//
#include <hip/hip_runtime.h>

typedef __attribute__((ext_vector_type(8))) short bf16x8;
typedef __attribute__((ext_vector_type(4))) float f32x4;

__device__ __forceinline__ unsigned short f2bf(float f) {
    unsigned int u = __builtin_bit_cast(unsigned int, f);
    u += 0x7fffu + ((u >> 16) & 1u);   // round-to-nearest-even
    return (unsigned short)(u >> 16);
}

// Kernel 1: A[i][j] = (i==j) ? 0 : sum_d w[i,field[j],d] * w[j,field[i],d]
// Symmetric, bit-identical across the diagonal. Packed bf16 in MFMA fragment
// order: apk[((kt*8+nt)*64+lane)*8+r] <-> A[kt*32+(lane>>4)*8+r][nt*16+(lane&15)].
// By symmetry the same packing is the A-operand fragment (row-block nt, k-block kt).
__global__ void build_A_kernel(const float* __restrict__ w, const int* __restrict__ field,
                               unsigned short* __restrict__ apk) {
    int idx = blockIdx.x * 128 + threadIdx.x;   // 0..16383
    int i = idx >> 7, j = idx & 127;
    const float* wi = w + (i * 16 + field[j]) * 16;
    const float* wj = w + (j * 16 + field[i]) * 16;
    float s = 0.f;
#pragma unroll
    for (int d = 0; d < 16; ++d) s += wi[d] * wj[d];
    if (i == j) s = 0.f;
    int kt = i >> 5, g = (i >> 3) & 3, r = i & 7;
    int nt = j >> 4, c = j & 15;
    apk[((kt * 8 + nt) * 64 + (g * 16 + c)) * 8 + r] = f2bf(s);
}

// Kernel 2: barrier-free. B-operand loaded DIRECTLY from global x into regs
// (lane (g,c) needs X[m0+c][kt*32+g*8..+7] = 32B contiguous), converted to
// bf16 in-register. LDS only for the epilogue X redistribution: per-WAVE
// private 8KB fp32 scratch (no __syncthreads; same-wave DS ordering).
// XOR swizzle on 16B chunks: phys_chunk = logical_chunk ^ (c&7) within each
// 128B window -> writes and reads both hit 8 distinct bank-quads (floor).
__global__ __launch_bounds__(256, 2)
void ffm_kernel(const float* __restrict__ x, const unsigned short* __restrict__ apk,
                float* __restrict__ out, int nTiles) {
    __shared__ __align__(16) float Xe[4 * 16 * 128];   // 32 KiB, per-wave 16x128 f32
    const int tid  = threadIdx.x;
    const int lane = tid & 63;
    const int wv   = tid >> 6;     // wave owns rows [wv*16, wv*16+16) of each tile
    const int g    = lane >> 4;
    const int c    = lane & 15;

    const int tile0 = blockIdx.x * 4;
    if (tile0 >= nTiles) return;

    const f32x4* xv4 = reinterpret_cast<const f32x4*>(x);
    // f32x4 index of this lane's row-chunk base within tile T:
    //   (T*64 + wv*16 + c)*32 + kt*8 + g*2 + h
    const size_t rowv = (size_t)(wv * 16 + c) * 32 + (size_t)g * 2;

    // Issue first-tile loads immediately (long pole: cold HBM).
    f32x4 xr[2][8];
    {
        size_t base = (size_t)tile0 * 2048 + rowv;
#pragma unroll
        for (int kt = 0; kt < 4; ++kt) {
            xr[0][kt * 2]     = xv4[base + kt * 8];
            xr[0][kt * 2 + 1] = xv4[base + kt * 8 + 1];
        }
    }

    // A fragments (32 KiB chip-wide, L2/L3-hot after first touch). 128 VGPR.
    bf16x8 bfrag[4][8];
#pragma unroll
    for (int kt = 0; kt < 4; ++kt)
#pragma unroll
        for (int q = 0; q < 8; ++q)
            bfrag[kt][q] = *reinterpret_cast<const bf16x8*>(apk + ((kt * 8 + q) * 64 + lane) * 8);

    const int ebase = wv * 2048 + c * 128;   // this lane's row base in Xe (floats)
    const int cs    = c & 7;                 // swizzle key

#pragma unroll
    for (int t = 0; t < 4; ++t) {
        int tile = tile0 + t;
        if (tile >= nTiles) break;
        const int cur = t & 1;

        // Prefetch next tile into the other register buffer (in flight across
        // convert + MFMA + epilogue; no barrier ever drains it).
        if (t < 3 && tile + 1 < nTiles) {
            size_t base = (size_t)(tile + 1) * 2048 + rowv;
#pragma unroll
            for (int kt = 0; kt < 4; ++kt) {
                xr[cur ^ 1][kt * 2]     = xv4[base + kt * 8];
                xr[cur ^ 1][kt * 2 + 1] = xv4[base + kt * 8 + 1];
            }
        }

        // Convert + MFMA: Yt = A(128x128) * X^T(128x16),
        // acc[q][r] = Y[m0+c][q*16 + g*4 + r].
        f32x4 acc[8];
#pragma unroll
        for (int q = 0; q < 8; ++q) acc[q] = (f32x4){0.f, 0.f, 0.f, 0.f};
#pragma unroll
        for (int kt = 0; kt < 4; ++kt) {
            f32x4 u0 = xr[cur][kt * 2];
            f32x4 u1 = xr[cur][kt * 2 + 1];
            bf16x8 xa;
            xa[0] = (short)f2bf(u0[0]); xa[1] = (short)f2bf(u0[1]);
            xa[2] = (short)f2bf(u0[2]); xa[3] = (short)f2bf(u0[3]);
            xa[4] = (short)f2bf(u1[0]); xa[5] = (short)f2bf(u1[1]);
            xa[6] = (short)f2bf(u1[2]); xa[7] = (short)f2bf(u1[3]);
#pragma unroll
            for (int q = 0; q < 8; ++q)
                acc[q] = __builtin_amdgcn_mfma_f32_16x16x32_bf16(bfrag[kt][q], xa, acc[q], 0, 0, 0);
        }

        // Stage this lane's fp32 row chunks to per-wave LDS (swizzled), then
        // read back the epilogue chunks. Same-wave ordering, no barrier.
#pragma unroll
        for (int kt = 0; kt < 4; ++kt)
#pragma unroll
            for (int h = 0; h < 2; ++h) {
                int wc = (g * 2 + h) ^ cs;
                *reinterpret_cast<f32x4*>(&Xe[ebase + kt * 32 + wc * 4]) = xr[cur][kt * 2 + h];
            }

        float sacc = 0.f;
#pragma unroll
        for (int q = 0; q < 8; ++q) {
            int ch  = q * 4 + g;                       // logical 16B chunk of the row
            int off = ebase + (ch >> 3) * 32 + ((ch & 7) ^ cs) * 4;
            f32x4 xs = *reinterpret_cast<const f32x4*>(&Xe[off]);
            sacc += xs[0] * acc[q][0] + xs[1] * acc[q][1]
                  + xs[2] * acc[q][2] + xs[3] * acc[q][3];
        }
        sacc += __shfl_xor(sacc, 16, 64);
        sacc += __shfl_xor(sacc, 32, 64);
        if (g == 0) out[(size_t)tile * 64 + wv * 16 + c] = 0.5f * sacc;
    }
}

extern "C" void kernel_launch(void* const* d_in, const int* in_sizes, int n_in,
                              void* d_out, int out_size, void* d_ws, size_t ws_size,
                              hipStream_t stream) {
    const float* x     = (const float*)d_in[0];
    const float* w     = (const float*)d_in[1];
    const int*   field = (const int*)d_in[2];
    float* outp        = (float*)d_out;
    unsigned short* apk = (unsigned short*)d_ws;   // 32 KiB packed A

    int B = in_sizes[0] / 128;
    build_A_kernel<<<128, 128, 0, stream>>>(w, field, apk);

    int nTiles = B / 64;                   // 2048 for B=131072
    int grid = (nTiles + 3) / 4;           // 512 blocks, 4 tiles each
    ffm_kernel<<<grid, 256, 0, stream>>>(x, apk, outp, nTiles);
}